// Round 1
// baseline (1256.695 us; speedup 1.0000x reference)
//
#include <hip/hip_runtime.h>

// Problem constants (from reference)
#define BATCH      262144
#define REC_STRIDE 300      // 15*20 floats per peptide record
#define A          20       // ALPHABET
#define P          34       // NUM_POCKETS
#define F          9        // FILTER
#define OUTW       28       // A + F - 1
#define NTHREADS   256
#define NREC       9        // max distinct batches spanned by 256 consecutive pairs
#define PEP_FLOATS 180      // rows 0..8 of a record (only rows used by the mask)

// One thread == one (b,p) pair. Blocks cover 256 consecutive global pair ids,
// so there is no tail round and no idle lanes in the compute phase.
// Output staging through LDS is gone: 28 floats/pair = 112 B is 16B-aligned,
// so each thread stores 7 float4 directly; a wave's 7 stores cover a dense
// 7168 B region that L2 write-combines.
__global__ __launch_bounds__(NTHREADS, 4)
void pep_pocket_conv(const float* __restrict__ pep,
                     const int*   __restrict__ pocket,
                     const float* __restrict__ kern,
                     float*       __restrict__ out)
{
    __shared__ float sPep[NREC * PEP_FLOATS];   // 6480 B
    __shared__ float sK[A * F];                 // 720 B  (total LDS ~7.2 KB)

    const int t  = threadIdx.x;
    const int pl = blockIdx.x * NTHREADS + t;   // global pair id
    const int b  = pl / P;                      // batch  (magic-mul)
    const int p  = pl - b * P;                  // pocket
    const int bFirst = (blockIdx.x * NTHREADS) / P;

    // Independent global load issued before the barrier: filter id per pair
    // (consecutive pl -> perfectly coalesced dword loads).
    const int c = pocket[pl];

    // Stage the shared 20x9 kernel table (45 float4)
    if (t < 45)
        *(float4*)&sK[t * 4] = *(const float4*)(kern + t * 4);

    // Stage rows 0..8 of the NREC records this block touches (float4, linear)
    for (int i = t; i < NREC * 45; i += NTHREADS) {
        const int rec = i / 45, v = i - rec * 45;
        int bb = bFirst + rec;
        if (bb >= BATCH) bb = BATCH - 1;        // clamp (last block only)
        *(float4*)&sPep[i * 4] =
            *(const float4*)(pep + (size_t)bb * REC_STRIDE + v * 4);
    }
    __syncthreads();

    // Aggregate the two mask rows for this pocket: rows {q, j2}, dedup at q==0.
    const int q  = p % F;                       // p % 9
    const int j2 = 3 * (p % 3);
    const float sel = (j2 != q) ? 1.f : 0.f;    // branchless dedup
    const float* base = &sPep[(b - bFirst) * PEP_FLOATS];
    const float* rA = base + q  * A;            // 80 B offsets: float4-aligned
    const float* rB = base + j2 * A;

    float a[A];
    #pragma unroll
    for (int v = 0; v < 5; ++v) {
        const float4 x = *(const float4*)(rA + v * 4);
        const float4 y = *(const float4*)(rB + v * 4);
        a[v * 4 + 0] = x.x + sel * y.x;
        a[v * 4 + 1] = x.y + sel * y.y;
        a[v * 4 + 2] = x.z + sel * y.z;
        a[v * 4 + 3] = x.w + sel * y.w;
    }

    float kf[F];
    #pragma unroll
    for (int f = 0; f < F; ++f) kf[f] = sK[c * F + f];

    // Full convolution in registers: acc[f+j] += kf[f]*a[j]
    float acc[OUTW];
    #pragma unroll
    for (int k = 0; k < OUTW; ++k) acc[k] = 0.f;
    #pragma unroll
    for (int f = 0; f < F; ++f) {
        #pragma unroll
        for (int j = 0; j < A; ++j)
            acc[f + j] += kf[f] * a[j];
    }

    // Direct vectorized writeout: 7 x float4 per pair (112 B, aligned)
    float4* op = (float4*)(out + (size_t)pl * OUTW);
    #pragma unroll
    for (int k = 0; k < 7; ++k)
        op[k] = make_float4(acc[4 * k + 0], acc[4 * k + 1],
                            acc[4 * k + 2], acc[4 * k + 3]);
}

extern "C" void kernel_launch(void* const* d_in, const int* in_sizes, int n_in,
                              void* d_out, int out_size, void* d_ws, size_t ws_size,
                              hipStream_t stream) {
    const float* pep    = (const float*)d_in[0];  // [B,15,20] fp32
    const int*   pocket = (const int*)d_in[1];    // [B,34] int32
    const float* kern   = (const float*)d_in[2];  // [20,9] fp32
    float* out = (float*)d_out;                   // [B,34,28] fp32

    const int grid = (BATCH * P) / NTHREADS;      // 8,912,896 / 256 = 34,816
    pep_pocket_conv<<<grid, NTHREADS, 0, stream>>>(pep, pocket, kern, out);
}